// Round 2
// baseline (68.739 us; speedup 1.0000x reference)
//
#include <hip/hip_runtime.h>
#include <math.h>

// Problem constants (from reference setup_inputs)
#define N_  2
#define C_  64
#define S_  4
#define H_  64
#define W_  44
#define HW_       (H_ * W_)          // 2816
#define CH_STRIDE (S_ * HW_)         // 11264 elements between channels
#define NSTRIDE   (C_ * S_ * HW_)    // 720896 elements between n-batches

typedef _Float16 h8 __attribute__((ext_vector_type(8)));
typedef float    f4 __attribute__((ext_vector_type(4)));

// Round 11: single fused kernel, NO workspace, NO staging LDS, NO pre-MFMA
// barrier.
//
// Round-10 insight: the MFMA fragment for lane (quad,l16) is 8 consecutive
// CHANNELS at one spatial position -> 8 channel-strided dwords loadable
// DIRECTLY from the f32 global tensors (each load instruction coalesces into
// 4 x 64B segments across the 4 quads). f32->f16 conversion happens in
// registers. This removes: the repack kernel (launch + dependency drain),
// the 256MB-workspace usage, the LDS staging slabs (72KB -> 8.6KB), and the
// first __syncthreads.
//
// Block = (b, y), 448 threads = 7 waves, wave w handles f1 row y+w-3.
// MFMA indexing identical to the harness-verified round-9/10 kernels:
//   A[m=l16+mi*16][k=(kh*4+quad)*8+j] = f0[ch=k][y][x=m]      (0 if x>=W)
//   B[k][n] = f1[ch=k][row][col=mi*16+nh*16-8+l16]            (0 outside)
//   D row m = quad*4+reg, col n = l16  ->  band |col-x|<=3 -> corr[x][w*7+dx]
// Then barrier, wave-0 softmax over 49 taps (verified path, unchanged).
__global__ __launch_bounds__(448) void flow_kernel(
    const float* __restrict__ f0,
    const float* __restrict__ f1,
    float* __restrict__ out)
{
    const int lane = threadIdx.x & 63;
    const int w    = threadIdx.x >> 6;      // 0..6 (one wave per f1 row)
    const int b    = blockIdx.x & 7;        // batch pinned per XCD slot
    const int y    = blockIdx.x >> 3;
    const int n_idx = b >> 2;
    const int s_idx = b & 3;
    const int base  = n_idx * NSTRIDE + s_idx * HW_;

    __shared__ float corr[W_][49];          // 8624 B — the only LDS

    const int row = y + w - 3;
    if (row >= 0 && row < H_) {
        const int quad = lane >> 4;
        const int l16  = lane & 15;

        // ---- A fragments: f0 row y, direct channel-gather + cvt ----
        h8 afr[3][2];
        #pragma unroll
        for (int mi = 0; mi < 3; ++mi) {
            const int  x  = mi * 16 + l16;
            const bool av = (x < W_);
            const float* pa = f0 + base + y * W_ + (av ? x : 0);
            #pragma unroll
            for (int kh = 0; kh < 2; ++kh) {
                const int ch0 = (kh * 4 + quad) * 8;
                float v[8];
                #pragma unroll
                for (int j = 0; j < 8; ++j)
                    v[j] = pa[(size_t)(ch0 + j) * CH_STRIDE];
                h8 a;
                #pragma unroll
                for (int j = 0; j < 8; ++j)
                    a[j] = av ? (_Float16)v[j] : (_Float16)0.0f;
                afr[mi][kh] = a;
            }
        }

        // ---- B fragments on the fly + 12 MFMAs ----
        const float* pb_row = f1 + base + row * W_;
        f4 acc[3][2];
        #pragma unroll
        for (int mi = 0; mi < 3; ++mi) {
            #pragma unroll
            for (int nh = 0; nh < 2; ++nh) {
                const int  col = mi * 16 + nh * 16 - 8 + l16;
                const bool bv  = (col >= 0) && (col < W_);
                const float* pb = pb_row + (bv ? col : 0);
                f4 a = {0.f, 0.f, 0.f, 0.f};
                #pragma unroll
                for (int kh = 0; kh < 2; ++kh) {
                    const int ch0 = (kh * 4 + quad) * 8;
                    float v[8];
                    #pragma unroll
                    for (int j = 0; j < 8; ++j)
                        v[j] = pb[(size_t)(ch0 + j) * CH_STRIDE];
                    h8 bf;
                    #pragma unroll
                    for (int j = 0; j < 8; ++j)
                        bf[j] = bv ? (_Float16)v[j] : (_Float16)0.0f;
                    a = __builtin_amdgcn_mfma_f32_16x16x32_f16(
                            afr[mi][kh], bf, a, 0, 0, 0);
                }
                acc[mi][nh] = a;
            }
        }

        // ---- band extraction: keep |col-x|<=3 -> corr[x][w*7+dx] ----
        #pragma unroll
        for (int mi = 0; mi < 3; ++mi) {
            #pragma unroll
            for (int nh = 0; nh < 2; ++nh) {
                #pragma unroll
                for (int r = 0; r < 4; ++r) {
                    const int x   = mi * 16 + quad * 4 + r;
                    const int col = mi * 16 + nh * 16 - 8 + l16;
                    const int dx  = col - x + 3;
                    if (x < W_ && dx >= 0 && dx < 7)
                        corr[x][w * 7 + dx] = acc[mi][nh][r] * 0.125f; // 1/sqrt(64)
                }
            }
        }
    }

    __syncthreads();

    // ---- wave 0: softmax over 49 taps + expected flow (verified path) ----
    if (w == 0) {
        const int xe = min(lane, W_ - 1);
        float c[49];
        float m = -1e30f;
        #pragma unroll
        for (int k = 0; k < 49; ++k) {
            const int kdy = k / 7, kdx = k % 7;
            const int col = lane + kdx - 3;
            const int rr  = y + kdy - 3;
            const bool ok = (col >= 0) && (col < W_) && (rr >= 0) && (rr < H_);
            const float v = ok ? corr[xe][k] : -1e30f;    // mask invalid taps
            c[k] = v;
            m = fmaxf(m, v);
        }
        float S = 0.0f, Sx = 0.0f, Sy = 0.0f;
        #pragma unroll
        for (int k = 0; k < 49; ++k) {
            const float e = __expf(c[k] - m);             // -1e30 -> 0
            S  += e;
            Sx += e * (float)(k % 7 - 3);
            Sy += e * (float)(k / 7 - 3);
        }
        if (lane < W_) {
            const float inv = 1.0f / S;
            // out layout: (n, 2, s, h, w)
            const int ob = (n_idx * 2) * S_ * HW_ + s_idx * HW_ + y * W_ + lane;
            out[ob]            = Sx * inv;                // flow x
            out[ob + S_ * HW_] = Sy * inv;                // flow y
        }
    }
}

extern "C" void kernel_launch(void* const* d_in, const int* in_sizes, int n_in,
                              void* d_out, int out_size, void* d_ws, size_t ws_size,
                              hipStream_t stream) {
    const float* f0 = (const float*)d_in[0];
    const float* f1 = (const float*)d_in[1];
    float* out = (float*)d_out;

    flow_kernel<<<8 * H_, 448, 0, stream>>>(f0, f1, out);  // 512 blocks x 7 waves
}

// Round 3
// 65.504 us; speedup vs baseline: 1.0494x; 1.0494x over previous
//
#include <hip/hip_runtime.h>
#include <math.h>

// Problem constants (from reference setup_inputs)
#define N_  2
#define C_  64
#define S_  4
#define H_  64
#define W_  44
#define HW_       (H_ * W_)          // 2816
#define CH_STRIDE (S_ * HW_)         // 11264 elements between channels
#define NSTRIDE   (C_ * S_ * HW_)    // 720896 elements between n-batches

typedef _Float16 h8 __attribute__((ext_vector_type(8)));
typedef float    f4 __attribute__((ext_vector_type(4)));

// Round 12: RESTORE the round-9 harness-verified best (66.0 us).
//
// Evidence from rounds 10/11: three structurally different kernels (LDS-staged
// MFMA / split repack+main / zero-staging direct gather) all land at 66-69 us,
// and the rocprof top-5 in every profiled round is the harness's 256 MiB
// workspace-poison fill (41 us at 82% of HBM peak — i.e. AT the achievable
// memory roofline), not our kernel. Conclusion: dur_us is dominated by
// fixed harness cost (fill + reset/launch overhead); kernel-side deltas are
// a few us at most. The round-9 structure was the fastest measured, so we
// return to it exactly.
//
// Structure: block = (b, y), 512 threads = 8 waves.
//   waves 0..6: stage f1 row y+w-3 into slabF1[w]: f16 [c8][xi<64][8ch]
//               (zero halo both sides -> MFMA needs no masking)
//   wave 7:     stage f0 row y into slabF0: f16 [c8][x<48][8ch] (pad 44..47)
// One barrier, then per wave w<7: corr[x, col] = sum_ch f0[ch,x]*f1row[ch,col]
// via 12 v_mfma_f32_16x16x32_f16 (3 M-tiles x 2 N-halves x 2 K-halves).
// Band |col-x|<=3 -> corr[x][w*7+dx]; barrier; wave 0: 49-tap softmax + flow.
__global__ __launch_bounds__(512) void flow_kernel(
    const float* __restrict__ f0,
    const float* __restrict__ f1,
    float* __restrict__ out)
{
    const int lane = threadIdx.x & 63;
    const int w    = threadIdx.x >> 6;          // 0..7

    // b = blockIdx & 7: batch pinned per XCD slot for L2 locality
    const int b = blockIdx.x & 7;
    const int y = blockIdx.x >> 3;
    const int n_idx = b >> 2;
    const int s_idx = b & 3;
    const int base  = n_idx * NSTRIDE + s_idx * HW_;

    __shared__ __align__(16) _Float16 slabF1[7 * 8 * 64 * 8];  // 57344 B
    __shared__ __align__(16) _Float16 slabF0[8 * 48 * 8];      //  6144 B
    __shared__ float corr[W_][49];                             //  8624 B

    const int row     = y + w - 3;                 // staging row for w<7
    const bool row_ok = (row >= 0) && (row < H_);

    // ---- Phase 1: stage (one global round-trip per wave) ----
    if (w < 7) {
        if (row_ok) {
            const int col   = lane - 8;            // xi = lane, col = xi-8
            const bool vld  = (col >= 0) && (col < W_);
            const int cc    = min(max(col, 0), W_ - 1);
            const float* p  = f1 + base + row * W_ + cc;
            float v[64];
            #pragma unroll
            for (int j = 0; j < 64; ++j)           // all issued before any wait
                v[j] = p[(size_t)j * CH_STRIDE];
            #pragma unroll
            for (int c8 = 0; c8 < 8; ++c8) {
                h8 pk;
                #pragma unroll
                for (int j = 0; j < 8; ++j)
                    pk[j] = vld ? (_Float16)v[c8 * 8 + j] : (_Float16)0.0f;
                *(h8*)&slabF1[((w * 8 + c8) * 64 + lane) * 8] = pk;
            }
        }
    } else {
        if (lane < 48) {                           // x = lane, zero-pad 44..47
            const bool vld = (lane < W_);
            const int  xc  = min(lane, W_ - 1);
            const float* p = f0 + base + y * W_ + xc;
            float v[64];
            #pragma unroll
            for (int j = 0; j < 64; ++j)
                v[j] = p[(size_t)j * CH_STRIDE];
            #pragma unroll
            for (int c8 = 0; c8 < 8; ++c8) {
                h8 pk;
                #pragma unroll
                for (int j = 0; j < 8; ++j)
                    pk[j] = vld ? (_Float16)v[c8 * 8 + j] : (_Float16)0.0f;
                *(h8*)&slabF0[(c8 * 48 + lane) * 8] = pk;
            }
        }
    }

    __syncthreads();   // all rows + f0 staged

    // ---- Phase 2: MFMA band GEMM (waves 0..6 with valid rows) ----
    if (w < 7 && row_ok) {
        const int quad = lane >> 4;
        const int l16  = lane & 15;

        // A fragments: f0, per (m-tile, k-half)
        h8 afr[3][2];
        #pragma unroll
        for (int mi = 0; mi < 3; ++mi)
            #pragma unroll
            for (int kh = 0; kh < 2; ++kh)
                afr[mi][kh] = *(const h8*)
                    &slabF0[((kh * 4 + quad) * 48 + (mi * 16 + l16)) * 8];

        const _Float16* myslab = &slabF1[w * (8 * 64 * 8)];
        f4 acc[3][2];
        #pragma unroll
        for (int mi = 0; mi < 3; ++mi) {
            #pragma unroll
            for (int nh = 0; nh < 2; ++nh) {
                f4 a = {0.f, 0.f, 0.f, 0.f};
                #pragma unroll
                for (int kh = 0; kh < 2; ++kh) {
                    const h8 bfr = *(const h8*)
                        &myslab[((kh * 4 + quad) * 64 + (mi * 16 + nh * 16 + l16)) * 8];
                    a = __builtin_amdgcn_mfma_f32_16x16x32_f16(afr[mi][kh], bfr, a, 0, 0, 0);
                }
                acc[mi][nh] = a;
            }
        }

        // band extraction: D[m=x][n=col], keep |col-x|<=3 -> corr[x][w*7+dx]
        #pragma unroll
        for (int mi = 0; mi < 3; ++mi) {
            #pragma unroll
            for (int nh = 0; nh < 2; ++nh) {
                #pragma unroll
                for (int r = 0; r < 4; ++r) {
                    const int x   = mi * 16 + quad * 4 + r;
                    const int col = mi * 16 + nh * 16 - 8 + l16;
                    const int dx  = col - x + 3;
                    if (x < W_ && dx >= 0 && dx < 7)
                        corr[x][w * 7 + dx] = acc[mi][nh][r] * 0.125f;  // 1/sqrt(64)
                }
            }
        }
    }

    __syncthreads();

    // ---- Phase 3: wave 0 softmax over 49 taps + expected flow ----
    if (w == 0) {
        const int xe = min(lane, W_ - 1);
        float c[49];
        float m = -1e30f;
        #pragma unroll
        for (int k = 0; k < 49; ++k) {
            const int kdy = k / 7, kdx = k % 7;
            const int col = lane + kdx - 3;
            const int rr  = y + kdy - 3;
            const bool ok = (col >= 0) && (col < W_) && (rr >= 0) && (rr < H_);
            const float v = ok ? corr[xe][k] : -1e30f;    // mask invalid taps
            c[k] = v;
            m = fmaxf(m, v);
        }
        float S = 0.0f, Sx = 0.0f, Sy = 0.0f;
        #pragma unroll
        for (int k = 0; k < 49; ++k) {
            const float e = __expf(c[k] - m);             // -1e30 -> 0
            S  += e;
            Sx += e * (float)(k % 7 - 3);
            Sy += e * (float)(k / 7 - 3);
        }
        if (lane < W_) {
            const float inv = 1.0f / S;
            // out layout: (n, 2, s, h, w)
            const int ob = (n_idx * 2) * S_ * HW_ + s_idx * HW_ + y * W_ + lane;
            out[ob]            = Sx * inv;                // flow x
            out[ob + S_ * HW_] = Sy * inv;                // flow y
        }
    }
}

extern "C" void kernel_launch(void* const* d_in, const int* in_sizes, int n_in,
                              void* d_out, int out_size, void* d_ws, size_t ws_size,
                              hipStream_t stream) {
    const float* f0 = (const float*)d_in[0];
    const float* f1 = (const float*)d_in[1];
    float* out = (float*)d_out;

    flow_kernel<<<8 * H_, 512, 0, stream>>>(f0, f1, out);  // 512 blocks x 8 waves
}